// Round 7
// baseline (201.744 us; speedup 1.0000x reference)
//
#include <hip/hip_runtime.h>

#define NB 32
#define NN 64
#define ND 256
#define MH 32   // rows (j) per k2 block after M-split
constexpr float PEN = 10000.0f;
constexpr float TEMP_ = 0.05f;

typedef __bf16 bfrag __attribute__((ext_vector_type(8)));   // 8 bf16 = 4 VGPR (MFMA A/B)
typedef float  f32x4 __attribute__((ext_vector_type(4)));   // MFMA C/D

__device__ __forceinline__ float clip50(float x) { return fminf(fmaxf(x, -50.0f), 50.0f); }
__device__ __forceinline__ ushort bfbits(__bf16 h) { return __builtin_bit_cast(ushort, h); }
__device__ __forceinline__ float bf2f(__bf16 h) {
    return __builtin_bit_cast(float, (uint)bfbits(h) << 16);
}
// round-to-nearest-even f32 -> bf16 bit pattern (pack kernel only)
__device__ __forceinline__ ushort bf16_rne(float x) {
    uint u = __builtin_bit_cast(uint, x);
    return (ushort)((u + 0x7fffu + ((u >> 16) & 1u)) >> 16);
}
__device__ __forceinline__ void split2(float a, float b, uint& h, uint& l) {
    const ushort ha = bf16_rne(a), hb = bf16_rne(b);
    const float fa = __builtin_bit_cast(float, (uint)ha << 16);
    const float fb = __builtin_bit_cast(float, (uint)hb << 16);
    const ushort la = bf16_rne(a - fa), lb = bf16_rne(b - fb);
    h = (uint)ha | ((uint)hb << 16);
    l = (uint)la | ((uint)lb << 16);
}
// LDS A/B-plane swizzle: element (row m, col k) bf16 at byte m*512 + (2k ^ ((m&7)<<4))
#define ASW(m, k2) ((m) * 512 + ((k2) ^ (((m) & 7) << 4)))

// ---------------- K01: U/V GEMMs (blocks 0..511) + W-pack (blocks 512..551) ----
__global__ __launch_bounds__(256)
void k01_uv_pack(const float* __restrict__ s_t, const float* __restrict__ s_t1,
                 const float* __restrict__ W1, const float* __restrict__ b1,
                 const float* __restrict__ W2, float* __restrict__ U,
                 float* __restrict__ V, ushort* __restrict__ w1h,
                 ushort* __restrict__ w1l, ushort* __restrict__ w2h,
                 ushort* __restrict__ w2l)
{
    const int tid = threadIdx.x;
    if (blockIdx.x >= 512) {
        // ---- pack W1c (8192 threads) and W2 (2048 threads) into frag order ----
        const int gid = (blockIdx.x - 512) * 256 + tid;
        const float* srcW; ushort *dh, *dl;
        int fb, kt, col, kbase, stride, base;
        if (gid < 8192) {            // W1c: fb = kt*16 + ctile, kt<8, ctile<16
            fb = gid >> 6; kt = fb >> 4;
            const int ntg = fb & 15, ln = gid & 63;
            col = ntg * 16 + (ln & 15); kbase = kt * 32 + (ln >> 4) * 8;
            srcW = W1 + 2 * ND * ND; stride = ND; dh = w1h; dl = w1l; base = gid * 8;
        } else {                     // W2: fb = kt*4 + ntile, kt<8, ntile<4
            const int g2 = gid - 8192;
            fb = g2 >> 6; kt = fb >> 2;
            const int ntg = fb & 3, ln = g2 & 63;
            col = ntg * 16 + (ln & 15); kbase = kt * 32 + (ln >> 4) * 8;
            srcW = W2; stride = 64; dh = w2h; dl = w2l; base = g2 * 8;
        }
        uint hv[4], lv[4];
        #pragma unroll
        for (int p = 0; p < 4; ++p) {
            const float a = srcW[(kbase + 2 * p) * stride + col];
            const float b = srcW[(kbase + 2 * p + 1) * stride + col];
            split2(a, b, hv[p], lv[p]);
        }
        *(uint4*)(dh + base) = make_uint4(hv[0], hv[1], hv[2], hv[3]);
        *(uint4*)(dl + base) = make_uint4(lv[0], lv[1], lv[2], lv[3]);
        return;
    }
    // ---- U/V: 512 blocks, 16-row x 128-col tiles (fp32 exact) ----
    const int half = blockIdx.x >> 8;
    const int rem  = blockIdx.x & 255;
    const int rb   = rem >> 1;
    const int colh = rem & 1;
    const float* src = half ? s_t1 : s_t;
    const float* W   = W1 + half * ND * ND;
    float* dst = half ? V : U;
    __shared__ float sL[16 * ND];
    const int rbase = rb * 16;
    #pragma unroll
    for (int t = 0; t < 4; ++t) {
        const int i4 = ((t << 8) + tid) << 2;
        float4 a = *(const float4*)(src + rbase * ND + i4);
        a.x = clip50(a.x); a.y = clip50(a.y); a.z = clip50(a.z); a.w = clip50(a.w);
        *(float4*)(sL + i4) = a;
    }
    __syncthreads();
    const int wv   = tid >> 6;
    const int lane = tid & 63;
    const int tj1  = lane >> 5;
    const int tc   = lane & 31;
    const int r0   = wv * 4 + tj1 * 2;
    const int c0   = colh * 128 + tc * 4;
    float acc[2][4] = {};
    for (int k4 = 0; k4 < ND; k4 += 4) {
        float4 sv[2];
        #pragma unroll
        for (int r = 0; r < 2; ++r) sv[r] = *(const float4*)(sL + (r0 + r) * ND + k4);
        #pragma unroll
        for (int kk = 0; kk < 4; ++kk) {
            const float4 wvv = *(const float4*)(W + (k4 + kk) * ND + c0);
            #pragma unroll
            for (int r = 0; r < 2; ++r) {
                const float s = (&sv[r].x)[kk];
                acc[r][0] = fmaf(s, wvv.x, acc[r][0]);
                acc[r][1] = fmaf(s, wvv.y, acc[r][1]);
                acc[r][2] = fmaf(s, wvv.z, acc[r][2]);
                acc[r][3] = fmaf(s, wvv.w, acc[r][3]);
            }
        }
    }
    float4 bias = make_float4(0.f, 0.f, 0.f, 0.f);
    if (!half) bias = *(const float4*)(b1 + c0);
    #pragma unroll
    for (int r = 0; r < 2; ++r) {
        float4 o;
        o.x = acc[r][0] + bias.x; o.y = acc[r][1] + bias.y;
        o.z = acc[r][2] + bias.z; o.w = acc[r][3] + bias.w;
        *(float4*)(dst + (rbase + r0 + r) * ND + c0) = o;
    }
}

// ---------------- K2: per-(b,i,jh) pair-MLP via split-bf16 MFMA ----------------
// Phase 2 operand-swapped: A = W1c^T (M-dim = c), B = diff (N-dim = j).
// Round 7: explicit 2-stage W prefetch across kt + pre-barrier kt=0 prefetch,
// attacking barrier-exposed L2 latency. Everything else as round 6.
__global__ __launch_bounds__(256, 4)
void k2_scores(const float* __restrict__ s_t, const float* __restrict__ s_t1,
               const float* __restrict__ b2, const float* __restrict__ W3,
               const float* __restrict__ b3, const float* __restrict__ alive_t,
               const float* __restrict__ alive_t1,
               const float* __restrict__ U, const float* __restrict__ V,
               const ushort* __restrict__ w1h, const ushort* __restrict__ w1l,
               const ushort* __restrict__ w2h, const ushort* __restrict__ w2l,
               float* __restrict__ laG)
{
    __shared__ ushort sAh[MH * ND];    // 16 KB
    __shared__ ushort sAl[MH * ND];    // 16 KB
    __shared__ float  red[4 * MH];     // 512 B
    const int tid = threadIdx.x;
    const int bi  = blockIdx.x >> 1;
    const int jh  = blockIdx.x & 1;
    const int b   = bi >> 6;
    const int jbase = jh * MH;
    const int lane = tid & 63;
    const int w    = tid >> 6;
    const int mlane = lane & 15;
    const int kg    = lane >> 4;

    // ---- phase 1: diff = |clip(s_t[i]) - clip(s_t1[jbase+m])| -> hi/lo planes ----
    {
        const float* stb = s_t + bi * ND;
        const float* s1b = s_t1 + (size_t)b * NN * ND + (size_t)jbase * ND;
        #pragma unroll
        for (int t = 0; t < 4; ++t) {
            const int slot = (t << 8) + tid;       // 1024 slots of 8 k
            const int m  = slot >> 5;              // local row 0..31
            const int k0 = (slot & 31) << 3;
            const float4 a0 = *(const float4*)(stb + k0);
            const float4 a1 = *(const float4*)(stb + k0 + 4);
            const float4 p0 = *(const float4*)(s1b + m * ND + k0);
            const float4 p1 = *(const float4*)(s1b + m * ND + k0 + 4);
            float d[8];
            d[0] = fabsf(clip50(a0.x) - clip50(p0.x));
            d[1] = fabsf(clip50(a0.y) - clip50(p0.y));
            d[2] = fabsf(clip50(a0.z) - clip50(p0.z));
            d[3] = fabsf(clip50(a0.w) - clip50(p0.w));
            d[4] = fabsf(clip50(a1.x) - clip50(p1.x));
            d[5] = fabsf(clip50(a1.y) - clip50(p1.y));
            d[6] = fabsf(clip50(a1.z) - clip50(p1.z));
            d[7] = fabsf(clip50(a1.w) - clip50(p1.w));
            uint hv[4], lv[4];
            #pragma unroll
            for (int p = 0; p < 4; ++p) {
                const __bf16 ha = (__bf16)d[2*p], hb = (__bf16)d[2*p+1];
                const __bf16 la_ = (__bf16)(d[2*p]   - bf2f(ha));
                const __bf16 lb_ = (__bf16)(d[2*p+1] - bf2f(hb));
                hv[p] = (uint)bfbits(ha) | ((uint)bfbits(hb) << 16);
                lv[p] = (uint)bfbits(la_) | ((uint)bfbits(lb_) << 16);
            }
            const int off = ASW(m, k0 * 2);
            *(uint4*)((char*)sAh + off) = make_uint4(hv[0], hv[1], hv[2], hv[3]);
            *(uint4*)((char*)sAl + off) = make_uint4(lv[0], lv[1], lv[2], lv[3]);
        }
    }

    // ---- prefetch kt=0 W1 A-frags BEFORE the barrier (no LDS dependency) ----
    bfrag WAh[2][4], WAl[2][4];
    #pragma unroll
    for (int ct = 0; ct < 4; ++ct) {
        const int fo = ((w << 2) + ct) * 512 + lane * 8;     // kt = 0
        WAh[0][ct] = *(const bfrag*)(w1h + fo);
        WAl[0][ct] = *(const bfrag*)(w1l + fo);
    }
    __syncthreads();

    // ---- phase 2 (swapped): D[c][j] = sum_k W1c[k][c] * diff[j][k] ----
    f32x4 acc[4][2];   // [ct][jt]
    #pragma unroll
    for (int ct = 0; ct < 4; ++ct)
        #pragma unroll
        for (int jt = 0; jt < 2; ++jt)
            #pragma unroll
            for (int r = 0; r < 4; ++r) acc[ct][jt][r] = 0.f;
    #pragma unroll
    for (int kt = 0; kt < 8; ++kt) {
        const int cur = kt & 1, nxt = cur ^ 1;
        // prefetch next kt's W frags (2-stage ping-pong)
        if (kt < 7) {
            #pragma unroll
            for (int ct = 0; ct < 4; ++ct) {
                const int fo = ((kt + 1) * 16 + (w << 2) + ct) * 512 + lane * 8;
                WAh[nxt][ct] = *(const bfrag*)(w1h + fo);
                WAl[nxt][ct] = *(const bfrag*)(w1l + fo);
            }
        }
        const int k2b = (kt * 32 + kg * 8) * 2;
        bfrag Bh[2], Bl[2];
        #pragma unroll
        for (int jt = 0; jt < 2; ++jt) {
            const int off = ASW(jt * 16 + mlane, k2b);
            Bh[jt] = *(const bfrag*)((const char*)sAh + off);
            Bl[jt] = *(const bfrag*)((const char*)sAl + off);
        }
        #pragma unroll
        for (int ct = 0; ct < 4; ++ct)
            #pragma unroll
            for (int jt = 0; jt < 2; ++jt) {
                acc[ct][jt] = __builtin_amdgcn_mfma_f32_16x16x32_bf16(WAh[cur][ct], Bh[jt], acc[ct][jt], 0, 0, 0);
                acc[ct][jt] = __builtin_amdgcn_mfma_f32_16x16x32_bf16(WAh[cur][ct], Bl[jt], acc[ct][jt], 0, 0, 0);
                acc[ct][jt] = __builtin_amdgcn_mfma_f32_16x16x32_bf16(WAl[cur][ct], Bh[jt], acc[ct][jt], 0, 0, 0);
            }
    }
    __syncthreads();   // all phase-2 B reads done before h1 overwrites planes

    // ---- epilogue: h1 = relu(D + U[bi,c] + V[b,jbase+j,c]) -> hi/lo planes ----
    {
        const float* Ur = U + (size_t)bi * ND;
        const float* Vb = V + (size_t)b * NN * ND + (size_t)jbase * ND;
        #pragma unroll
        for (int ct = 0; ct < 4; ++ct) {
            const int c0 = (w << 6) + ct * 16 + (kg << 2);
            const float4 uq = *(const float4*)(Ur + c0);
            #pragma unroll
            for (int jt = 0; jt < 2; ++jt) {
                const int j = jt * 16 + mlane;         // local row
                const float4 vq = *(const float4*)(Vb + (size_t)j * ND + c0);
                float x[4];
                x[0] = fmaxf(acc[ct][jt][0] + uq.x + vq.x, 0.f);
                x[1] = fmaxf(acc[ct][jt][1] + uq.y + vq.y, 0.f);
                x[2] = fmaxf(acc[ct][jt][2] + uq.z + vq.z, 0.f);
                x[3] = fmaxf(acc[ct][jt][3] + uq.w + vq.w, 0.f);
                const __bf16 h0 = (__bf16)x[0], h1v = (__bf16)x[1];
                const __bf16 h2 = (__bf16)x[2], h3 = (__bf16)x[3];
                const __bf16 l0 = (__bf16)(x[0] - bf2f(h0)), l1 = (__bf16)(x[1] - bf2f(h1v));
                const __bf16 l2 = (__bf16)(x[2] - bf2f(h2)), l3 = (__bf16)(x[3] - bf2f(h3));
                uint2 hq, lq;
                hq.x = (uint)bfbits(h0) | ((uint)bfbits(h1v) << 16);
                hq.y = (uint)bfbits(h2) | ((uint)bfbits(h3) << 16);
                lq.x = (uint)bfbits(l0) | ((uint)bfbits(l1) << 16);
                lq.y = (uint)bfbits(l2) | ((uint)bfbits(l3) << 16);
                const int off = ASW(j, c0 * 2);
                *(uint2*)((char*)sAh + off) = hq;
                *(uint2*)((char*)sAl + off) = lq;
            }
        }
    }

    // ---- prefetch kt=0 W2 frags BEFORE the barrier ----
    bfrag W2hS[2], W2lS[2];
    {
        const int fo = w * 512 + lane * 8;                   // kt = 0
        W2hS[0] = *(const bfrag*)(w2h + fo);
        W2lS[0] = *(const bfrag*)(w2l + fo);
    }
    __syncthreads();

    // ---- phase 3: C2 = h1 @ W2 (wave w -> N-tile w, both M-tiles) ----
    f32x4 acc2[2];
    #pragma unroll
    for (int mt = 0; mt < 2; ++mt)
        #pragma unroll
        for (int r = 0; r < 4; ++r) acc2[mt][r] = 0.f;
    #pragma unroll
    for (int kt = 0; kt < 8; ++kt) {
        const int cur = kt & 1, nxt = cur ^ 1;
        if (kt < 7) {
            const int fo = ((kt + 1) * 4 + w) * 512 + lane * 8;
            W2hS[nxt] = *(const bfrag*)(w2h + fo);
            W2lS[nxt] = *(const bfrag*)(w2l + fo);
        }
        const int k2b = (kt * 32 + kg * 8) * 2;
        #pragma unroll
        for (int mt = 0; mt < 2; ++mt) {
            const int m = mt * 16 + mlane;
            const int off = ASW(m, k2b);
            const bfrag Ah = *(const bfrag*)((const char*)sAh + off);
            const bfrag Al = *(const bfrag*)((const char*)sAl + off);
            acc2[mt] = __builtin_amdgcn_mfma_f32_16x16x32_bf16(Ah, W2hS[cur], acc2[mt], 0, 0, 0);
            acc2[mt] = __builtin_amdgcn_mfma_f32_16x16x32_bf16(Ah, W2lS[cur], acc2[mt], 0, 0, 0);
            acc2[mt] = __builtin_amdgcn_mfma_f32_16x16x32_bf16(Al, W2hS[cur], acc2[mt], 0, 0, 0);
        }
    }

    // ---- final: h2 = relu(C2 + b2); partial score = sum_m h2*W3 ----
    {
        const int m = w * 16 + mlane;
        const float b2v = b2[m];
        const float w3v = W3[m];
        #pragma unroll
        for (int mt = 0; mt < 2; ++mt) {
            #pragma unroll
            for (int r = 0; r < 4; ++r) {
                const int j = mt * 16 + (kg << 2) + r;     // local row
                float val = fmaxf(acc2[mt][r] + b2v, 0.f) * w3v;
                val += __shfl_xor(val, 1, 64);
                val += __shfl_xor(val, 2, 64);
                val += __shfl_xor(val, 4, 64);
                val += __shfl_xor(val, 8, 64);
                if (mlane == 0) red[w * MH + j] = val;
            }
        }
    }
    __syncthreads();
    if (tid < MH) {
        const int j = tid;                                 // local row
        const float sc = red[j] + red[MH + j] + red[2 * MH + j] + red[3 * MH + j] + b3[0];
        const float pen_i = (alive_t[bi] < 0.5f) ? PEN : 0.0f;
        const float pj = (alive_t1[b * NN + jbase + j] < 0.5f) ? PEN : 0.0f;
        const float sp = sc - pen_i - pj;
        laG[bi * NN + jbase + j] = fminf(fmaxf(sp, -PEN), PEN) / TEMP_;
    }
}

// ---------------- K3: Sinkhorn (20 iters) + argmax/matched, 512 threads ----------------
__global__ __launch_bounds__(512)
void k3_sinkhorn(const float* __restrict__ laG, const float* __restrict__ alive_t,
                 const float* __restrict__ alive_t1, float* __restrict__ out)
{
    __shared__ float la[NN * 65];          // pad 65: both passes conflict-free
    const int b = blockIdx.x, tid = threadIdx.x;
    for (int idx = tid; idx < NN * NN; idx += 512)
        la[(idx >> 6) * 65 + (idx & 63)] = laG[b * NN * NN + idx];
    __syncthreads();

    const int g = tid >> 3;                // row/col index 0..63
    const int q = tid & 7;                 // eighth (8 elements each)
    for (int it = 0; it < 20; ++it) {
        {   // axis=2: normalize rows (over c)
            float m = -INFINITY;
            #pragma unroll
            for (int t = 0; t < 8; ++t) m = fmaxf(m, la[g * 65 + q * 8 + t]);
            m = fmaxf(m, __shfl_xor(m, 1, 64));
            m = fmaxf(m, __shfl_xor(m, 2, 64));
            m = fmaxf(m, __shfl_xor(m, 4, 64));
            float s = 0.f;
            #pragma unroll
            for (int t = 0; t < 8; ++t) s += expf(la[g * 65 + q * 8 + t] - m);
            s += __shfl_xor(s, 1, 64);
            s += __shfl_xor(s, 2, 64);
            s += __shfl_xor(s, 4, 64);
            const float lse = m + logf(s);
            #pragma unroll
            for (int t = 0; t < 8; ++t) la[g * 65 + q * 8 + t] -= lse;
        }
        __syncthreads();
        {   // axis=1: normalize cols (over r)
            float m = -INFINITY;
            #pragma unroll
            for (int t = 0; t < 8; ++t) m = fmaxf(m, la[(q * 8 + t) * 65 + g]);
            m = fmaxf(m, __shfl_xor(m, 1, 64));
            m = fmaxf(m, __shfl_xor(m, 2, 64));
            m = fmaxf(m, __shfl_xor(m, 4, 64));
            float s = 0.f;
            #pragma unroll
            for (int t = 0; t < 8; ++t) s += expf(la[(q * 8 + t) * 65 + g] - m);
            s += __shfl_xor(s, 1, 64);
            s += __shfl_xor(s, 2, 64);
            s += __shfl_xor(s, 4, 64);
            const float lse = m + logf(s);
            #pragma unroll
            for (int t = 0; t < 8; ++t) la[(q * 8 + t) * 65 + g] -= lse;
        }
        __syncthreads();
    }

    // argmax over axis 2 with first-index tie-break
    float bm = -INFINITY; int bidx = 0;
    #pragma unroll
    for (int t = 0; t < 8; ++t) {
        const float v = la[g * 65 + q * 8 + t];
        if (v > bm) { bm = v; bidx = q * 8 + t; }
    }
    #pragma unroll
    for (int off = 1; off < 8; off <<= 1) {
        const float om = __shfl_xor(bm, off, 64);
        const int   oi = __shfl_xor(bidx, off, 64);
        if (om > bm || (om == bm && oi < bidx)) { bm = om; bidx = oi; }
    }
    if (q == 0) {
        const float conf = expf(bm);
        const float at  = alive_t[b * NN + g];
        const float at1 = alive_t1[b * NN + bidx];
        const float matched = (at > 0.5f && at1 > 0.5f && conf > 0.3f) ? 1.0f : 0.0f;
        out[b * NN + g] = (float)bidx;                 // perm (written as float)
        out[NB * NN + b * NN + g] = matched;           // matched
    }
}

extern "C" void kernel_launch(void* const* d_in, const int* in_sizes, int n_in,
                              void* d_out, int out_size, void* d_ws, size_t ws_size,
                              hipStream_t stream)
{
    (void)in_sizes; (void)n_in; (void)out_size; (void)ws_size;
    const float* s_t      = (const float*)d_in[0];
    const float* s_t1     = (const float*)d_in[1];
    const float* alive_t  = (const float*)d_in[2];
    const float* alive_t1 = (const float*)d_in[3];
    const float* W1 = (const float*)d_in[4];
    const float* b1 = (const float*)d_in[5];
    const float* W2 = (const float*)d_in[6];
    const float* b2 = (const float*)d_in[7];
    const float* W3 = (const float*)d_in[8];
    const float* b3 = (const float*)d_in[9];

    char* ws = (char*)d_ws;
    float*  U   = (float*)(ws);                         // 2 MB
    float*  V   = (float*)(ws + 2097152);               // 2 MB
    float*  laG = (float*)(ws + 4194304);               // 512 KB
    ushort* w1h = (ushort*)(ws + 4718592);              // 128 KB
    ushort* w1l = (ushort*)(ws + 4849664);              // 128 KB
    ushort* w2h = (ushort*)(ws + 4980736);              // 32 KB
    ushort* w2l = (ushort*)(ws + 5013504);              // 32 KB
    float* out = (float*)d_out;

    hipLaunchKernelGGL(k01_uv_pack, dim3(552), dim3(256), 0, stream,
                       s_t, s_t1, W1, b1, W2, U, V, w1h, w1l, w2h, w2l);
    hipLaunchKernelGGL(k2_scores, dim3(NB * NN * 2), dim3(256), 0, stream,
                       s_t, s_t1, b2, W3, b3, alive_t, alive_t1, U, V,
                       w1h, w1l, w2h, w2l, laG);
    hipLaunchKernelGGL(k3_sinkhorn, dim3(NB), dim3(512), 0, stream,
                       laG, alive_t, alive_t1, out);
}